// Round 2
// baseline (1011.104 us; speedup 1.0000x reference)
//
#include <hip/hip_runtime.h>

#define LEVELS 16
#define TSIZE 524288
#define TMASK (TSIZE - 1)
#define TPB 256
#define GPPT 8                  // gather: points per thread
#define CHUNK (TPB * GPPT)      // 2048 points per chunk/slab

typedef float f2v __attribute__((ext_vector_type(2)));
typedef float f4v __attribute__((ext_vector_type(4)));

// int(16 * 1.5**l), exact as float32
__device__ __constant__ float c_res[LEVELS] = {
    16.f, 24.f, 36.f, 54.f, 81.f, 121.f, 182.f, 273.f,
    410.f, 615.f, 922.f, 1383.f, 2075.f, 3113.f, 4670.f, 7006.f
};

__device__ __forceinline__ unsigned hash_idx(float px, float py, float pz, float r)
{
    const int ix = (int)floorf(px * r);
    const int iy = (int)floorf(py * r);
    const int iz = (int)floorf(pz * r);
    const unsigned h = (unsigned)ix * 73856093u
                     ^ (unsigned)iy * 19349663u
                     ^ (unsigned)iz * 83492791u;
    return h & TMASK;
}

// ws layout: [flags: reserve bytes][slabs: ws[(c*LEVELS + l)*CHUNK + local]]
//
// ---------------- Fused kernel: XCD-pinned gather + lookback assemble -------
// grid = 2 halves x 8 x bpl, dispatch order: all half-0 gathers first, then
// half-1. Block b: level = half*8 + (b%8) -> XCD-pinned tables (4MB/XCD L2).
//
// Round-7: gather is at its outstanding-miss-capacity floor (~64 lines/CU x
// latency model matches 240us to within 3%). The separate assemble kernel
// serialized another 88us of the SAME shared resource + an independent
// write-side limit. Fuse: after a block's slab stores drain, it bumps
// cnt[c] (agent-release). The 8 half-1 blocks of chunk c (dispatched
// adjacently; their half-0 producers retired ~8192 blocks earlier) each
// spin briefly on cnt[c]==16 then assemble a 256-point slice of chunk c.
// No agent-acquire (would buffer_inv the XCD L2 and evict the pinned
// table): ws is nontemporal on BOTH sides, so no cache holds ws copies and
// reads observe the release-fenced data at L3/HBM.
__global__ __launch_bounds__(TPB) void fused_gather_assemble(
    const float* __restrict__ x,
    const float* __restrict__ tables,
    unsigned* __restrict__ cnt,
    f2v* __restrict__ ws,
    float* __restrict__ out,
    int n, int bpl)
{
    const int b = blockIdx.x;
    const int half = b / (8 * bpl);
    const int r = b % (8 * bpl);
    const int q = r & 7;                    // XCD pin / half-level index
    const int level = half * 8 + q;
    const int c = r >> 3;                   // chunk id
    const int t = threadIdx.x;

    const float rs = c_res[level];
    const float* __restrict__ tbl = tables + (size_t)level * (TSIZE * 2);
    f2v* __restrict__ slab = ws + ((size_t)c * LEVELS + level) * CHUNK;
    const long long base = (long long)c * CHUNK;

    if (base + CHUNK <= n) {
        // -------- fast path: full chunk, phase-batched for deep MLP --------
        const float* __restrict__ xb = x + 3 * base;

        float px[GPPT], py[GPPT], pz[GPPT];
#pragma unroll
        for (int j = 0; j < GPPT; ++j) {
            const int local = j * TPB + t;
            px[j] = xb[3 * local + 0];
            py[j] = xb[3 * local + 1];
            pz[j] = xb[3 * local + 2];
        }

        unsigned idx[GPPT];
#pragma unroll
        for (int j = 0; j < GPPT; ++j)
            idx[j] = hash_idx(px[j], py[j], pz[j], rs);

        f2v e[GPPT];
#pragma unroll
        for (int j = 0; j < GPPT; ++j)
            e[j] = *reinterpret_cast<const f2v*>(tbl + 2 * (size_t)idx[j]);

#pragma unroll
        for (int j = 0; j < GPPT; ++j)
            __builtin_nontemporal_store(e[j], slab + j * TPB + t);
    } else {
        // -------- tail path: guarded --------
#pragma unroll
        for (int j = 0; j < GPPT; ++j) {
            const int local = j * TPB + t;
            const long long p = base + local;
            if (p < n) {
                const float qx = x[3 * p + 0];
                const float qy = x[3 * p + 1];
                const float qz = x[3 * p + 2];
                const unsigned idx = hash_idx(qx, qy, qz, rs);
                const f2v e = *reinterpret_cast<const f2v*>(tbl + 2 * (size_t)idx);
                __builtin_nontemporal_store(e, slab + local);
            }
        }
    }

    // -------- publish this slab (all waves' stores drained by the barrier) --
    __syncthreads();
    if (t == 0)
        __hip_atomic_fetch_add(&cnt[c], 1u, __ATOMIC_RELEASE,
                               __HIP_MEMORY_SCOPE_AGENT);

    if (half == 0) return;

    // -------- duty: half-1 block q assembles points [q*256, q*256+256) -----
    if (t == 0) {
        while (__hip_atomic_load(&cnt[c], __ATOMIC_RELAXED,
                                 __HIP_MEMORY_SCOPE_AGENT) < (unsigned)LEVELS)
            __builtin_amdgcn_s_sleep(8);
    }
    __syncthreads();

    const int qq = t & 7;                   // slab pair (levels 2qq, 2qq+1)
    const int sub = t >> 3;                 // 0..31
    const f2v* __restrict__ wa = ws + ((size_t)c * LEVELS + 2 * qq) * CHUNK;
    const f2v* __restrict__ wb = wa + CHUNK;
    const int sb = q * (CHUNK / 8);         // slice base: 256 points

    if (base + CHUNK <= n) {
        // fast: 2 points per lane per iter, 4 iters = 256 points
#pragma unroll
        for (int u = 0; u < CHUNK / 8 / 64; ++u) {
            const int lp = sb + 2 * (u * 32 + sub);
            const f4v a = __builtin_nontemporal_load(
                reinterpret_cast<const f4v*>(wa + lp));
            const f4v bb = __builtin_nontemporal_load(
                reinterpret_cast<const f4v*>(wb + lp));
            f4v v0, v1;
            v0.x = a.x; v0.y = a.y; v0.z = bb.x; v0.w = bb.y;
            v1.x = a.z; v1.y = a.w; v1.z = bb.z; v1.w = bb.w;
            float* row = out + (size_t)(base + lp) * (2 * LEVELS) + 4 * qq;
            __builtin_nontemporal_store(v0, reinterpret_cast<f4v*>(row));
            __builtin_nontemporal_store(v1, reinterpret_cast<f4v*>(row + 2 * LEVELS));
        }
    } else {
        // tail: guarded f2v, 8 iters = 256 points
#pragma unroll
        for (int u = 0; u < CHUNK / 8 / 32; ++u) {
            const int lp = sb + u * 32 + sub;
            const long long pt = base + lp;
            if (pt < n) {
                const f2v a = __builtin_nontemporal_load(wa + lp);
                const f2v bb = __builtin_nontemporal_load(wb + lp);
                f4v v;
                v.x = a.x; v.y = a.y; v.z = bb.x; v.w = bb.y;
                __builtin_nontemporal_store(
                    v, reinterpret_cast<f4v*>(out + (size_t)pt * (2 * LEVELS) + 4 * qq));
            }
        }
    }
}

// ---------------- Fallback (ws too small): round-3 fused kernel --------------
#define ROWW 34
__global__ __launch_bounds__(TPB) void hashgrid_fused(
    const float* __restrict__ x,
    const float* __restrict__ tables,
    float* __restrict__ out,
    int n)
{
    __shared__ float lds[TPB * ROWW];
    const int t = threadIdx.x;

    for (long long base = (long long)blockIdx.x * TPB; base < n;
         base += (long long)gridDim.x * TPB) {
        const int p = (int)base + t;
        float px = 0.f, py = 0.f, pz = 0.f;
        if (p < n) {
            px = x[3 * (size_t)p + 0];
            py = x[3 * (size_t)p + 1];
            pz = x[3 * (size_t)p + 2];
        }
#pragma unroll
        for (int l = 0; l < LEVELS; ++l) {
            if (p < n) {
                const unsigned idx = hash_idx(px, py, pz, c_res[l]);
                const f2v e = *reinterpret_cast<const f2v*>(
                    tables + (((size_t)l * TSIZE + idx) << 1));
                *reinterpret_cast<f2v*>(lds + t * ROWW + 2 * l) = e;
            }
            __syncthreads();
        }
#pragma unroll
        for (int it = 0; it < 8; ++it) {
            const int lp = it * 32 + (t >> 3);
            const int qq = t & 7;
            const int gp = (int)base + lp;
            if (gp < n) {
                const f2v a = *reinterpret_cast<const f2v*>(lds + lp * ROWW + 4 * qq);
                const f2v b = *reinterpret_cast<const f2v*>(lds + lp * ROWW + 4 * qq + 2);
                f4v v;
                v.x = a.x; v.y = a.y; v.z = b.x; v.w = b.y;
                __builtin_nontemporal_store(
                    v, reinterpret_cast<f4v*>(out + (size_t)gp * (2 * LEVELS) + 4 * qq));
            }
        }
        __syncthreads();
    }
}

extern "C" void kernel_launch(void* const* d_in, const int* in_sizes, int n_in,
                              void* d_out, int out_size, void* d_ws, size_t ws_size,
                              hipStream_t stream)
{
    const float* x      = (const float*)d_in[0];   // [N, 3]
    const float* tables = (const float*)d_in[1];   // [L, T, F]
    float* out          = (float*)d_out;           // [N, L*F]
    const int n = in_sizes[0] / 3;

    const int bpl = (n + CHUNK - 1) / CHUNK;       // chunks (= blocks per level)
    // flag region at ws head, 256B-aligned, then slabs
    const size_t cnt_bytes = ((size_t)bpl * sizeof(unsigned) + 255) & ~(size_t)255;
    const size_t ws_need = cnt_bytes + (size_t)bpl * LEVELS * CHUNK * sizeof(f2v);
    if (ws_size < ws_need) {
        int grid = 1024;
        const int nblocks = (n + TPB - 1) / TPB;
        if (nblocks < grid) grid = nblocks;
        hashgrid_fused<<<grid, TPB, 0, stream>>>(x, tables, out, n);
        return;
    }

    unsigned* cnt = (unsigned*)d_ws;
    f2v* ws = (f2v*)((char*)d_ws + cnt_bytes);

    hipMemsetAsync(d_ws, 0, cnt_bytes, stream);    // graph-safe, re-zeroed per launch
    fused_gather_assemble<<<2 * 8 * bpl, TPB, 0, stream>>>(
        x, tables, cnt, ws, out, n, bpl);
}

// Round 3
// 348.967 us; speedup vs baseline: 2.8974x; 2.8974x over previous
//
#include <hip/hip_runtime.h>

#define LEVELS 16
#define TSIZE 524288
#define TMASK (TSIZE - 1)
#define TPB 256
#define GPPT 8                  // gather: points per thread
#define CHUNK (TPB * GPPT)      // 2048 points per chunk/slab

typedef float f2v __attribute__((ext_vector_type(2)));
typedef float f4v __attribute__((ext_vector_type(4)));

// int(16 * 1.5**l), exact as float32
__device__ __constant__ float c_res[LEVELS] = {
    16.f, 24.f, 36.f, 54.f, 81.f, 121.f, 182.f, 273.f,
    410.f, 615.f, 922.f, 1383.f, 2075.f, 3113.f, 4670.f, 7006.f
};

__device__ __forceinline__ unsigned hash_idx(float px, float py, float pz, float r)
{
    const int ix = (int)floorf(px * r);
    const int iy = (int)floorf(py * r);
    const int iz = (int)floorf(pz * r);
    const unsigned h = (unsigned)ix * 73856093u
                     ^ (unsigned)iy * 19349663u
                     ^ (unsigned)iz * 83492791u;
    return h & TMASK;
}

// ws layout: chunk-tiled slabs  ws[(c*LEVELS + l)*CHUNK + local]
// -> a chunk's 16 level slabs are contiguous (16KB apart, 256KB window):
//    kills the 16MiB power-of-two stream spacing that caused channel camping.

// ---------------- Kernel A: XCD-pinned level-major gather --------------------
// grid = 2 halves x 8 x bpl. Block b: level = half*8 + (b%8).
// Round-robin dispatch puts b%8==k on XCD k -> each XCD's 4MB L2 serves one
// 4MB table per half (round-5-proven: FETCH 1.9GB -> 0.55GB vs naive).
//
// Round-6: phase-batched fast path (8 gathers in flight). Round-7 (fusion
// with spin-flags) regressed 3x: spinning blocks destroy resident-block miss
// parallelism and agent-release atomics stall the pinned L2s -> reverted.
// Round-8: x loads are NONTEMPORAL. x has zero L2 reuse in this schedule
// (each chunk's x is read once per XCD visit), but the cached x stream was
// evicting lines of the pinned table (FETCH residue ~60MB above accountable
// minimum). NT keeps the table resident at zero cost to x.
__global__ __launch_bounds__(TPB) void gather_kernel(
    const float* __restrict__ x,
    const float* __restrict__ tables,
    f2v* __restrict__ ws,
    int n, int bpl)
{
    const int b = blockIdx.x;
    const int half = b / (8 * bpl);
    const int r = b % (8 * bpl);
    const int level = half * 8 + (r & 7);
    const int c = r >> 3;                   // chunk id
    const int t = threadIdx.x;

    const float rs = c_res[level];
    const float* __restrict__ tbl = tables + (size_t)level * (TSIZE * 2);
    f2v* __restrict__ slab = ws + ((size_t)c * LEVELS + level) * CHUNK;
    const long long base = (long long)c * CHUNK;

    if (base + CHUNK <= n) {
        // -------- fast path: full chunk, phase-batched for deep MLP --------
        const float* __restrict__ xb = x + 3 * base;

        float px[GPPT], py[GPPT], pz[GPPT];
#pragma unroll
        for (int j = 0; j < GPPT; ++j) {
            const int local = j * TPB + t;
            px[j] = __builtin_nontemporal_load(xb + 3 * local + 0);
            py[j] = __builtin_nontemporal_load(xb + 3 * local + 1);
            pz[j] = __builtin_nontemporal_load(xb + 3 * local + 2);
        }

        unsigned idx[GPPT];
#pragma unroll
        for (int j = 0; j < GPPT; ++j)
            idx[j] = hash_idx(px[j], py[j], pz[j], rs);

        // 8 independent random 8B gathers in flight (all hit XCD-local L2)
        f2v e[GPPT];
#pragma unroll
        for (int j = 0; j < GPPT; ++j)
            e[j] = *reinterpret_cast<const f2v*>(tbl + 2 * (size_t)idx[j]);

#pragma unroll
        for (int j = 0; j < GPPT; ++j)
            __builtin_nontemporal_store(e[j], slab + j * TPB + t);
    } else {
        // -------- tail path: original guarded loop --------
#pragma unroll
        for (int j = 0; j < GPPT; ++j) {
            const int local = j * TPB + t;
            const long long p = base + local;
            if (p < n) {
                const float qx = __builtin_nontemporal_load(x + 3 * p + 0);
                const float qy = __builtin_nontemporal_load(x + 3 * p + 1);
                const float qz = __builtin_nontemporal_load(x + 3 * p + 2);
                const unsigned idx = hash_idx(qx, qy, qz, rs);
                const f2v e = *reinterpret_cast<const f2v*>(tbl + 2 * (size_t)idx);
                __builtin_nontemporal_store(e, slab + local);
            }
        }
    }
}

// ---------------- Kernel B: assemble (slab ws -> point-major out rows) -------
// Block = one 2048-point chunk. Lane q=t&7 supplies quads 4q..4q+3 (levels
// 2q,2q+1). f4v-widened: each lane handles 2 points per iter (one 16B load
// per slab, two 16B full-row stores) at exact-output WRITE_SIZE, no RMW.
// Measured at ~5.6-5.9 TB/s -> at HBM roofline for its 524MB of traffic.
__global__ __launch_bounds__(TPB) void assemble_kernel(
    const f2v* __restrict__ ws,
    float* __restrict__ out,
    int n)
{
    const int c = blockIdx.x;
    const int t = threadIdx.x;
    const int q = t & 7;
    const int sub = t >> 3;  // 0..31

    const f2v* __restrict__ wa = ws + ((size_t)c * LEVELS + 2 * q) * CHUNK;
    const f2v* __restrict__ wb = wa + CHUNK;
    const long long base = (long long)c * CHUNK;

    if (base + CHUNK <= n) {
        // fast path: 2 points per lane per iter, no guards
#pragma unroll 8
        for (int u = 0; u < CHUNK / 64; ++u) {
            const int lp = 2 * (u * 32 + sub);
            const f4v a = __builtin_nontemporal_load(
                reinterpret_cast<const f4v*>(wa + lp));
            const f4v b = __builtin_nontemporal_load(
                reinterpret_cast<const f4v*>(wb + lp));
            f4v v0, v1;
            v0.x = a.x; v0.y = a.y; v0.z = b.x; v0.w = b.y;
            v1.x = a.z; v1.y = a.w; v1.z = b.z; v1.w = b.w;
            float* row = out + (size_t)(base + lp) * (2 * LEVELS) + 4 * q;
            __builtin_nontemporal_store(v0, reinterpret_cast<f4v*>(row));
            __builtin_nontemporal_store(v1, reinterpret_cast<f4v*>(row + 2 * LEVELS));
        }
    } else {
        // tail path: guarded f2v loop
#pragma unroll 8
        for (int u = 0; u < CHUNK / 32; ++u) {
            const int lp = u * 32 + sub;
            const long long pt = base + lp;
            if (pt < n) {
                const f2v a = __builtin_nontemporal_load(wa + lp);
                const f2v b = __builtin_nontemporal_load(wb + lp);
                f4v v;
                v.x = a.x; v.y = a.y; v.z = b.x; v.w = b.y;
                __builtin_nontemporal_store(
                    v, reinterpret_cast<f4v*>(out + (size_t)pt * (2 * LEVELS) + 4 * q));
            }
        }
    }
}

// ---------------- Fallback (ws too small): round-3 fused kernel --------------
#define ROWW 34
__global__ __launch_bounds__(TPB) void hashgrid_fused(
    const float* __restrict__ x,
    const float* __restrict__ tables,
    float* __restrict__ out,
    int n)
{
    __shared__ float lds[TPB * ROWW];
    const int t = threadIdx.x;

    for (long long base = (long long)blockIdx.x * TPB; base < n;
         base += (long long)gridDim.x * TPB) {
        const int p = (int)base + t;
        float px = 0.f, py = 0.f, pz = 0.f;
        if (p < n) {
            px = x[3 * (size_t)p + 0];
            py = x[3 * (size_t)p + 1];
            pz = x[3 * (size_t)p + 2];
        }
#pragma unroll
        for (int l = 0; l < LEVELS; ++l) {
            if (p < n) {
                const unsigned idx = hash_idx(px, py, pz, c_res[l]);
                const f2v e = *reinterpret_cast<const f2v*>(
                    tables + (((size_t)l * TSIZE + idx) << 1));
                *reinterpret_cast<f2v*>(lds + t * ROWW + 2 * l) = e;
            }
            __syncthreads();
        }
#pragma unroll
        for (int it = 0; it < 8; ++it) {
            const int lp = it * 32 + (t >> 3);
            const int qq = t & 7;
            const int gp = (int)base + lp;
            if (gp < n) {
                const f2v a = *reinterpret_cast<const f2v*>(lds + lp * ROWW + 4 * qq);
                const f2v b = *reinterpret_cast<const f2v*>(lds + lp * ROWW + 4 * qq + 2);
                f4v v;
                v.x = a.x; v.y = a.y; v.z = b.x; v.w = b.y;
                __builtin_nontemporal_store(
                    v, reinterpret_cast<f4v*>(out + (size_t)gp * (2 * LEVELS) + 4 * qq));
            }
        }
        __syncthreads();
    }
}

extern "C" void kernel_launch(void* const* d_in, const int* in_sizes, int n_in,
                              void* d_out, int out_size, void* d_ws, size_t ws_size,
                              hipStream_t stream)
{
    const float* x      = (const float*)d_in[0];   // [N, 3]
    const float* tables = (const float*)d_in[1];   // [L, T, F]
    float* out          = (float*)d_out;           // [N, L*F]
    const int n = in_sizes[0] / 3;

    const int bpl = (n + CHUNK - 1) / CHUNK;       // chunks (= blocks per level)
    const size_t ws_need = (size_t)bpl * LEVELS * CHUNK * sizeof(f2v);
    if (ws_size < ws_need) {
        int grid = 1024;
        const int nblocks = (n + TPB - 1) / TPB;
        if (nblocks < grid) grid = nblocks;
        hashgrid_fused<<<grid, TPB, 0, stream>>>(x, tables, out, n);
        return;
    }

    f2v* ws = (f2v*)d_ws;
    gather_kernel<<<2 * 8 * bpl, TPB, 0, stream>>>(x, tables, ws, n, bpl);
    assemble_kernel<<<bpl, TPB, 0, stream>>>(ws, out, n);
}